// Round 1
// baseline (2797.610 us; speedup 1.0000x reference)
//
#include <hip/hip_runtime.h>
#include <stdint.h>

// Viterbi CRF decode, batch element 63 only (reference returns scores[-1], paths[-1]).
// feats: [64,1024,512] f32, transitions: [512,512] f32, lengths: [64] int.
// out: [0]=score (f32), [1..1024]=path as f32 (-1 for t>=len).

#define KK 512
#define TMAX 1024
#define STARTT 510
#define STOPT 511
#define NEGINF (-10000.0f)
#define NWG 32
#define ROWS 16   // rows per WG

// ws layout
#define WS_FV 0                      // uint64 fvbuf[8][512]  (32 KB)
#define WS_RFLAG 32768               // int rflag[32] stride 32 ints (4 KB)
#define WS_BEST 36864                // int best
#define WS_BP 40960                  // uint16 bp[1024][512]  (1 MB)
#define WS_E (40960 + 1048576)       // uint16 E[64][512]     (64 KB)

__device__ __forceinline__ int read_len(const void* lp) {
  // lengths may be int32 or int64; int64 little-endian has hi-word 0 at odd int32 slots
  const int* q = (const int*)lp;
  return (q[1] == 0) ? (int)(((const long long*)lp)[63]) : q[63];
}

__global__ void k_init(char* ws) {
  uint64_t* fvb = (uint64_t*)(ws + WS_FV);
  int tid = threadIdx.x;  // 512
  float v = (tid == STARTT) ? 0.0f : NEGINF;
  fvb[tid] = (uint64_t)__float_as_uint(v);  // tag 0 in hi32
#pragma unroll
  for (int b = 1; b < 8; ++b) fvb[b * KK + tid] = 0x7FFFFFFF00000000ull;
  if (tid < NWG) ((int*)(ws + WS_RFLAG))[tid * 32] = -1;
}

__global__ void __launch_bounds__(512) k_forward(
    const float* __restrict__ feats, const float* __restrict__ trans,
    const void* __restrict__ lens, float* __restrict__ out, char* ws) {
  const int len = read_len(lens);
  const int g = blockIdx.x;
  const int tid = threadIdx.x;
  const int lane = tid & 63;
  const int c = tid & 31;                 // lane within row-group
  const int grow = g * ROWS + (tid >> 5); // global destination row i
  uint64_t* fvb = (uint64_t*)(ws + WS_FV);
  int* rflag = (int*)(ws + WS_RFLAG);
  uint16_t* bp = (uint16_t*)(ws + WS_BP);
  __shared__ float fvs[2][KK];
  __shared__ float redv[8];
  __shared__ int redi[8];

  // transitions slice resident in registers: row grow, cols c+32k
  float tr[16];
#pragma unroll
  for (int k = 0; k < 16; ++k) tr[k] = trans[grow * KK + c + 32 * k];

  const float* fb = feats + 63ll * TMAX * KK;  // batch 63
  const bool leader = (c == 0);
  float featNext = leader ? fb[grow] : 0.0f;

  for (int t = 0; t < len; ++t) {
    const int par = t & 7;
    const int sb = t & 1;
    // 1. spin-stage one fv entry (tag == t means producer's step-t value arrived)
    uint64_t x;
    do {
      x = __hip_atomic_load(&fvb[par * KK + tid], __ATOMIC_ACQUIRE, __HIP_MEMORY_SCOPE_AGENT);
    } while ((int)(uint32_t)(x >> 32) != t);
    fvs[sb][tid] = __uint_as_float((uint32_t)x);
    __syncthreads();

    // 2. post read-completion, issue (lagged) gate loads
    if (tid == 0)
      __hip_atomic_store(&rflag[g * 32], t, __ATOMIC_RELEASE, __HIP_MEMORY_SCOPE_AGENT);
    int gf = 0x7fffffff;
    if (lane < NWG)
      gf = __hip_atomic_load(&rflag[lane * 32], __ATOMIC_RELAXED, __HIP_MEMORY_SCOPE_AGENT);

    const float featCur = featNext;
    if (leader && t + 1 < len) featNext = fb[(size_t)(t + 1) * KK + grow];

    // 3. compute: max/argmax over j = c + 32k (first-index tie-break)
    float bv = fvs[sb][c] + tr[0];
    int bj = c;
#pragma unroll
    for (int k = 1; k < 16; ++k) {
      float v2 = fvs[sb][c + 32 * k] + tr[k];
      if (v2 > bv) { bv = v2; bj = c + 32 * k; }
    }
#pragma unroll
    for (int m = 16; m >= 1; m >>= 1) {
      float ov = __shfl_xor(bv, m);
      int oj = __shfl_xor(bj, m);
      if (ov > bv || (ov == bv && oj < bj)) { bv = ov; bj = oj; }
    }

    // 4. write-slot safety gate: slot (t+1)&7 held tag t-7, read at step t-7
    const int need = t - 7;
    while (__any(gf < need)) {
      if (lane < NWG && gf < need)
        gf = __hip_atomic_load(&rflag[lane * 32], __ATOMIC_RELAXED, __HIP_MEMORY_SCOPE_AGENT);
    }

    // 5. publish new fv entry (tag t+1) + backpointer
    if (leader) {
      const float vit = bv + featCur;
      const uint64_t pk = ((uint64_t)(uint32_t)(t + 1) << 32) | (uint64_t)__float_as_uint(vit);
      __hip_atomic_store(&fvb[((t + 1) & 7) * KK + grow], pk, __ATOMIC_RELEASE, __HIP_MEMORY_SCOPE_AGENT);
      bp[(size_t)t * KK + grow] = (uint16_t)bj;
    }
  }

  if (g != 0) return;
  // terminal: score = max_j fv[j] + trans[STOP][j], best = first argmax
  {
    const int par = len & 7;
    uint64_t x;
    do {
      x = __hip_atomic_load(&fvb[par * KK + tid], __ATOMIC_ACQUIRE, __HIP_MEMORY_SCOPE_AGENT);
    } while ((int)(uint32_t)(x >> 32) != len);
    float tv = __uint_as_float((uint32_t)x) + trans[STOPT * KK + tid];
    int tj = tid;
#pragma unroll
    for (int m = 32; m >= 1; m >>= 1) {
      float ov = __shfl_xor(tv, m);
      int oj = __shfl_xor(tj, m);
      if (ov > tv || (ov == tv && oj < tj)) { tv = ov; tj = oj; }
    }
    if (lane == 0) { redv[tid >> 6] = tv; redi[tid >> 6] = tj; }
    __syncthreads();
    if (tid == 0) {
      float s = redv[0];
      int b = redi[0];
#pragma unroll
      for (int w = 1; w < 8; ++w)
        if (redv[w] > s || (redv[w] == s && redi[w] < b)) { s = redv[w]; b = redi[w]; }
      out[0] = s;
      *((int*)(ws + WS_BEST)) = b;
    }
  }
}

// speculative backtrack: per 16-step segment, walk all 512 possible entry tags
__global__ void __launch_bounds__(512) k_walk(const void* __restrict__ lens, char* ws) {
  const int len = read_len(lens);
  const uint16_t* bp = (const uint16_t*)(ws + WS_BP);
  uint16_t* E = (uint16_t*)(ws + WS_E);
  const int s = blockIdx.x;   // 64 segments
  const int k = threadIdx.x;  // 512 entry tags
  int tag = k;
  const int lo = s * 16;
  for (int t = lo + 15; t >= lo; --t)
    if (t < len) tag = bp[(size_t)t * KK + tag];
  E[s * KK + k] = (uint16_t)tag;
}

// compose segment maps from the top, then re-walk each segment and emit the path
__global__ void __launch_bounds__(64) k_emit(
    const void* __restrict__ lens, float* __restrict__ out, char* ws) {
  const int len = read_len(lens);
  const uint16_t* bp = (const uint16_t*)(ws + WS_BP);
  const uint16_t* E = (const uint16_t*)(ws + WS_E);
  __shared__ int entry[64];
  const int tid = threadIdx.x;
  if (tid == 0) {
    int st = *((const int*)(ws + WS_BEST));
    for (int s = 63; s >= 0; --s) { entry[s] = st; st = E[s * KK + st]; }
  }
  __syncthreads();
  {
    const int s = tid;
    int st = entry[s];
    for (int t = s * 16 + 15; t >= s * 16; --t) {
      if (t < len) {
        out[1 + t] = (float)st;
        st = bp[(size_t)t * KK + st];
      } else {
        out[1 + t] = -1.0f;
      }
    }
  }
}

extern "C" void kernel_launch(void* const* d_in, const int* in_sizes, int n_in,
                              void* d_out, int out_size, void* d_ws, size_t ws_size,
                              hipStream_t stream) {
  const float* feats = (const float*)d_in[0];
  const float* trans = (const float*)d_in[1];
  const void* lens = d_in[2];
  float* out = (float*)d_out;
  char* ws = (char*)d_ws;
  (void)in_sizes; (void)n_in; (void)out_size; (void)ws_size;

  k_init<<<1, 512, 0, stream>>>(ws);
  k_forward<<<NWG, 512, 0, stream>>>(feats, trans, lens, out, ws);
  k_walk<<<64, 512, 0, stream>>>(lens, ws);
  k_emit<<<1, 64, 0, stream>>>(lens, out, ws);
}

// Round 2
// 645.768 us; speedup vs baseline: 4.3322x; 4.3322x over previous
//
#include <hip/hip_runtime.h>
#include <stdint.h>

// Viterbi CRF decode, batch element 63 only (reference returns scores[-1], paths[-1]).
// feats: [64,1024,512] f32, transitions: [512,512] f32, lengths: [64] int.
// out: [0]=score (f32), [1..1024]=path as f32 (-1 for t>=len).
//
// Protocol: 256 waves (one per CU), 2 destination rows each. fv exchanged via
// 8-deep ring of 512 packed (tag<<32 | f32) words in ws, relaxed agent-scope
// atomics only. No barriers, no read-gate: a wave publishes tag t+1 only after
// observing ALL 512 entries at tag t, which (inductively) implies every wave's
// reads of the slot being overwritten (tag t-7) completed — depth 8 >= 2 safe.

#define KK 512
#define TMAX 1024
#define STARTT 510
#define STOPT 511
#define NEGINF (-10000.0f)
#define DSLOT 8

// ws layout
#define WS_FV 0                      // uint64 fvbuf[8][512]  (32 KB)
#define WS_BEST 32768                // int best
#define WS_BP 40960                  // uint16 bp[1024][512]  (1 MB)
#define WS_E (40960 + 1048576)       // uint16 E[64][512]     (64 KB)

__device__ __forceinline__ int read_len(const void* lp) {
  // lengths may be int32 or int64; int64 little-endian has hi-word 0 at odd int32 slots
  const int* q = (const int*)lp;
  return (q[1] == 0) ? (int)(((const long long*)lp)[63]) : q[63];
}

__global__ void k_init(char* ws) {
  uint64_t* fvb = (uint64_t*)(ws + WS_FV);
  int tid = threadIdx.x;  // 512
  float v = (tid == STARTT) ? 0.0f : NEGINF;
  fvb[tid] = (uint64_t)__float_as_uint(v);  // tag 0 in hi32
#pragma unroll
  for (int b = 1; b < DSLOT; ++b) fvb[b * KK + tid] = 0x7FFFFFFF00000000ull;
}

__global__ void __launch_bounds__(64) k_forward(
    const float* __restrict__ feats, const float* __restrict__ trans,
    const void* __restrict__ lens, float* __restrict__ out, char* ws) {
  const int len = read_len(lens);
  const int w = blockIdx.x;   // 0..255, one wave per WG
  const int l = threadIdx.x;  // 0..63
  const int c = l & 31;
  const int R = 2 * w + (l >> 5);  // my destination row
  uint64_t* fvb = (uint64_t*)(ws + WS_FV);
  uint16_t* bp = (uint16_t*)(ws + WS_BP);

  // transitions slice in registers: row R, cols c+32k
  float tr[16];
#pragma unroll
  for (int k = 0; k < 16; ++k) tr[k] = trans[(size_t)R * KK + c + 32 * k];

  const float* fb = feats + 63ll * TMAX * KK;  // batch 63
  const bool leader = (c == 0);
  float featNext = leader ? fb[R] : 0.0f;

  for (int t = 0; t < len; ++t) {
    uint64_t* slot = fvb + (size_t)(t & (DSLOT - 1)) * KK;
    // spin: lane l owns entries j = l + 64m; wave covers all 512
    uint64_t v[8];
    bool ok;
    do {
#pragma unroll
      for (int m = 0; m < 8; ++m)
        v[m] = __hip_atomic_load(&slot[l + 64 * m], __ATOMIC_RELAXED, __HIP_MEMORY_SCOPE_AGENT);
      ok = true;
#pragma unroll
      for (int m = 0; m < 8; ++m) ok = ok && ((int)(uint32_t)(v[m] >> 32) == t);
    } while (__any(!ok));
    float fvals[8];
#pragma unroll
    for (int m = 0; m < 8; ++m) fvals[m] = __uint_as_float((uint32_t)v[m]);

    const float featCur = featNext;
    if (leader && t + 1 < len) featNext = fb[(size_t)(t + 1) * KK + R];

    // cand j = c + 32k held by lane c+32(k&1), reg k>>1; ascending k = ascending j
    float bv;
    int bj;
#pragma unroll
    for (int k = 0; k < 16; ++k) {
      float fvk = __shfl(fvals[k >> 1], c + 32 * (k & 1));
      float cand = fvk + tr[k];
      if (k == 0) {
        bv = cand; bj = c;
      } else if (cand > bv) {
        bv = cand; bj = c + 32 * k;
      }
    }
    // reduce within 32-lane row group, first-index tie-break
#pragma unroll
    for (int m = 16; m >= 1; m >>= 1) {
      float ov = __shfl_xor(bv, m);
      int oj = __shfl_xor(bj, m);
      if (ov > bv || (ov == bv && oj < bj)) { bv = ov; bj = oj; }
    }
    if (leader) {
      const float vit = bv + featCur;
      const uint64_t pk = ((uint64_t)(uint32_t)(t + 1) << 32) | (uint64_t)__float_as_uint(vit);
      __hip_atomic_store(&fvb[(size_t)((t + 1) & (DSLOT - 1)) * KK + R], pk,
                         __ATOMIC_RELAXED, __HIP_MEMORY_SCOPE_AGENT);
      bp[(size_t)t * KK + R] = (uint16_t)bj;
    }
  }

  if (w != 0) return;
  // terminal: score = max_j fv[j] + trans[STOP][j], best = first argmax
  {
    uint64_t* slot = fvb + (size_t)(len & (DSLOT - 1)) * KK;
    uint64_t v[8];
    bool ok;
    do {
#pragma unroll
      for (int m = 0; m < 8; ++m)
        v[m] = __hip_atomic_load(&slot[l + 64 * m], __ATOMIC_RELAXED, __HIP_MEMORY_SCOPE_AGENT);
      ok = true;
#pragma unroll
      for (int m = 0; m < 8; ++m) ok = ok && ((int)(uint32_t)(v[m] >> 32) == len);
    } while (__any(!ok));
    float tv;
    int tj;
#pragma unroll
    for (int m = 0; m < 8; ++m) {
      float x = __uint_as_float((uint32_t)v[m]) + trans[(size_t)STOPT * KK + l + 64 * m];
      if (m == 0) {
        tv = x; tj = l;
      } else if (x > tv) {
        tv = x; tj = l + 64 * m;
      }
    }
#pragma unroll
    for (int m = 32; m >= 1; m >>= 1) {
      float ov = __shfl_xor(tv, m);
      int oj = __shfl_xor(tj, m);
      if (ov > tv || (ov == tv && oj < tj)) { tv = ov; tj = oj; }
    }
    if (l == 0) {
      out[0] = tv;
      *((int*)(ws + WS_BEST)) = tj;
    }
  }
}

// speculative backtrack: per 16-step segment, walk all 512 possible entry tags
__global__ void __launch_bounds__(512) k_walk(const void* __restrict__ lens, char* ws) {
  const int len = read_len(lens);
  const uint16_t* bp = (const uint16_t*)(ws + WS_BP);
  uint16_t* E = (uint16_t*)(ws + WS_E);
  const int s = blockIdx.x;   // 64 segments
  const int k = threadIdx.x;  // 512 entry tags
  int tag = k;
  const int lo = s * 16;
  for (int t = lo + 15; t >= lo; --t)
    if (t < len) tag = bp[(size_t)t * KK + tag];
  E[s * KK + k] = (uint16_t)tag;
}

// compose segment maps from the top, then re-walk each segment and emit the path
__global__ void __launch_bounds__(64) k_emit(
    const void* __restrict__ lens, float* __restrict__ out, char* ws) {
  const int len = read_len(lens);
  const uint16_t* bp = (const uint16_t*)(ws + WS_BP);
  const uint16_t* E = (const uint16_t*)(ws + WS_E);
  __shared__ int entry[64];
  const int tid = threadIdx.x;
  if (tid == 0) {
    int st = *((const int*)(ws + WS_BEST));
    for (int s = 63; s >= 0; --s) { entry[s] = st; st = E[s * KK + st]; }
  }
  __syncthreads();
  {
    const int s = tid;
    int st = entry[s];
    for (int t = s * 16 + 15; t >= s * 16; --t) {
      if (t < len) {
        out[1 + t] = (float)st;
        st = bp[(size_t)t * KK + st];
      } else {
        out[1 + t] = -1.0f;
      }
    }
  }
}

extern "C" void kernel_launch(void* const* d_in, const int* in_sizes, int n_in,
                              void* d_out, int out_size, void* d_ws, size_t ws_size,
                              hipStream_t stream) {
  const float* feats = (const float*)d_in[0];
  const float* trans = (const float*)d_in[1];
  const void* lens = d_in[2];
  float* out = (float*)d_out;
  char* ws = (char*)d_ws;
  (void)in_sizes; (void)n_in; (void)out_size; (void)ws_size;

  k_init<<<1, 512, 0, stream>>>(ws);
  k_forward<<<256, 64, 0, stream>>>(feats, trans, lens, out, ws);
  k_walk<<<64, 512, 0, stream>>>(lens, ws);
  k_emit<<<1, 64, 0, stream>>>(lens, out, ws);
}